// Round 1
// 232.266 us; speedup vs baseline: 1.0207x; 1.0207x over previous
//
#include <hip/hip_runtime.h>

// FinDiffNonUniform: out[n,b] = sum_{s<7} coef[n,s] * y[n + off[n,s], b]
// N=8192, B=4096, S=7, fp32.
//
// Round-3 diagnosis: VGPR_Count=36 proved the 14-row window was serialized
// to ONE live float4 buffer (32 regs went to the 8 accumulators) ->
// load/waitcnt(0)/consume chains, ~1 outstanding load per wave, 3.0 TB/s.
// Fix: R=2 (8-row window = 32 VGPRs payload, cheap to keep live) plus a
// compile-time memory barrier between the load batch and the FMA chain so
// the compiler CANNOT sink loads into the consumption -> 8 outstanding
// loads/wave guaranteed. XCD-bijective swizzle keeps the 4x L1/L2 read
// amplification inside the per-XCD L2; nontemporal stores keep the write
// stream from evicting the y window.

#define FD_N   8192
#define FD_B   4096
#define FD_S   7
#define FD_R   2
#define HALO   3
#define WIN    (FD_R + 2 * HALO)   // 8
#define NSTRIP (FD_N / FD_R)       // 4096
#define NCHUNK 4                   // 1024 floats per column chunk
#define NWG    (NSTRIP * NCHUNK)   // 16384 (divisible by 8 -> simple swizzle ok)
#define NXCD   8

typedef float v4f __attribute__((ext_vector_type(4)));

__global__ __launch_bounds__(256) void
_FinDiffNonUniform_51608327029442_kernel(const float* __restrict__ y,
                                         const float* __restrict__ coef,
                                         const int*   __restrict__ offs,
                                         float*       __restrict__ out) {
    // Bijective XCD swizzle: blocks with bid % 8 == k land on XCD k and
    // receive a CONTIGUOUS range of logical ids -> consecutive n-strips of
    // one column chunk stream through the same per-XCD L2.
    const int bid   = blockIdx.x;
    const int id    = (bid & (NXCD - 1)) * (NWG / NXCD) + (bid >> 3);
    const int strip = id & (NSTRIP - 1);
    const int chunk = id >> 12;                    // id / NSTRIP
    const int n0    = strip * FD_R;
    const int b     = (chunk << 10) + (threadIdx.x << 2);

    if (strip >= 2 && strip <= NSTRIP - 3) {
        // ---- interior fast path: centered [-3..3] stencil ----
        // Block-uniform coefficients -> scalar loads, issued first.
        float c[FD_R][FD_S];
#pragma unroll
        for (int r = 0; r < FD_R; ++r)
#pragma unroll
            for (int s = 0; s < FD_S; ++s)
                c[r][s] = coef[(size_t)(n0 + r) * FD_S + s];

        const float* ybase = y + (size_t)(n0 - HALO) * FD_B + b;

        // Issue ALL 8 row loads back-to-back.
        v4f w[WIN];
#pragma unroll
        for (int j = 0; j < WIN; ++j)
            w[j] = *reinterpret_cast<const v4f*>(ybase + (size_t)j * FD_B);

        // Compile-time barrier: loads cannot sink below this point, so all
        // 8 results must be live -> 8 outstanding vmem ops per wave.
        asm volatile("" ::: "memory");

        v4f acc[FD_R];
#pragma unroll
        for (int r = 0; r < FD_R; ++r)
            acc[r] = (v4f){0.f, 0.f, 0.f, 0.f};

        // Consume rows in ARRIVAL order: row j (global row n0-3+j) feeds
        // output r with stencil index s = j - r, s in [0,7).
#pragma unroll
        for (int j = 0; j < WIN; ++j) {
#pragma unroll
            for (int r = 0; r < FD_R; ++r) {
                const int s = j - r;
                if (s >= 0 && s < FD_S)
                    acc[r] += c[r][s] * w[j];
            }
        }

#pragma unroll
        for (int r = 0; r < FD_R; ++r)
            __builtin_nontemporal_store(
                acc[r], reinterpret_cast<v4f*>(out + (size_t)(n0 + r) * FD_B + b));
    } else {
        // ---- boundary strips: generic gather with real offsets ----
#pragma unroll
        for (int r = 0; r < FD_R; ++r) {
            const int n = n0 + r;
            v4f acc = (v4f){0.f, 0.f, 0.f, 0.f};
#pragma unroll
            for (int s = 0; s < FD_S; ++s) {
                const float cc = coef[(size_t)n * FD_S + s];   // block-uniform
                const int   o  = offs[(size_t)n * FD_S + s];
                const v4f   v  =
                    *reinterpret_cast<const v4f*>(y + (size_t)(n + o) * FD_B + b);
                acc += cc * v;
            }
            __builtin_nontemporal_store(
                acc, reinterpret_cast<v4f*>(out + (size_t)n * FD_B + b));
        }
    }
}

extern "C" void kernel_launch(void* const* d_in, const int* in_sizes, int n_in,
                              void* d_out, int out_size, void* d_ws, size_t ws_size,
                              hipStream_t stream) {
    const float* y    = (const float*)d_in[0];
    const float* coef = (const float*)d_in[1];
    const int*   offs = (const int*)d_in[2];
    float*       out  = (float*)d_out;

    _FinDiffNonUniform_51608327029442_kernel<<<NWG, 256, 0, stream>>>(y, coef, offs, out);
}